// Round 8
// baseline (281.959 us; speedup 1.0000x reference)
//
#include <hip/hip_runtime.h>
#include <hip/hip_bf16.h>
#include <math.h>

#define B_SZ   4096
#define H_LEN  256
#define D_DIM  128
#define K_HEADS 4
#define H1_DIM 512
#define H2_DIM 256
#define NUM_ITEMS 200000

#define CH     64     // history rows per chunk
#define NCH    4      // chunks
#define TP2    136    // bf16 tile row stride (shorts): 272 B, 16B-aligned
#define TPAD   132    // fp32 tile row stride (fallback kernel)

typedef __attribute__((ext_vector_type(8))) short bf16x8;   // 8 bf16 (4 VGPRs)
typedef __attribute__((ext_vector_type(4))) float f32x4;
typedef __attribute__((ext_vector_type(4))) float cf4;      // clang vec for nontemporal
typedef __attribute__((ext_vector_type(4))) unsigned cu4;   // clang vec for nontemporal

// Raw barrier: LDS-visibility only. __syncthreads() drains vmcnt(0) which
// would stall on the in-flight next-chunk prefetch loads (round-1/2 lesson).
#define LDS_BARRIER() do {                                   \
    asm volatile("s_waitcnt lgkmcnt(0)" ::: "memory");       \
    __builtin_amdgcn_s_barrier();                            \
} while (0)

__device__ __forceinline__ float bf2f(short s) {
    unsigned u = ((unsigned)(unsigned short)s) << 16;
    float f; __builtin_memcpy(&f, &u, 4); return f;
}

// ---------------------------------------------------------------------------
// Kernel 1 (primary): multi-interest extraction, bf16 gather + bf16 LDS tile.
// MINIMAL DIFF from the R6-verified 91 us kernel: ONLY the tile element type
// changed fp32->bf16 (17.4 KB vs 33.8 KB -> 7 blocks/CU vs 4). Accumulators,
// pooling indexing, epilogue, launch bounds all IDENTICAL to R6.
// Mechanism target: delivered gather BW 2.8 TB/s @4 blk/CU -> R3 showed the
// memory system sustains 4.3 TB/s at 7 blocks/CU.
// ---------------------------------------------------------------------------
__global__ __launch_bounds__(256, 4) void interest_kernel_bf16(
    const int*   __restrict__ cand_ids,   // (B,)
    const int*   __restrict__ hist,       // (B, H)
    const float* __restrict__ table,      // (NUM_ITEMS, D) fp32 (candv only)
    const __hip_bfloat16* __restrict__ tableB, // (NUM_ITEMS, D) bf16
    const float* __restrict__ Wp,         // (D, K) row-major
    __hip_bfloat16* __restrict__ Xbf)     // (B, 2D) bf16: [selected | cand]
{
    __shared__ __align__(16) short tileB[CH * TP2]; // 17408 B; tail-reused
    __shared__ float wpt[K_HEADS * D_DIM];// Wp^T [k][d]           2 KB
    __shared__ float exps4[CH * 4];       // exp(score) [h][k]     1 KB
    __shared__ float candv[D_DIM];        //                       512 B
    __shared__ int   rowids[H_LEN];       //                       1 KB
    __shared__ float lsumW[16];           // per-wave denom partials [w][k]
    __shared__ float simred[4][K_HEADS];
    __shared__ int   bestk;

    const int b    = blockIdx.x;
    const int t    = threadIdx.x;
    const int lane = t & 63, w = t >> 6;
    const int r    = t >> 2, q = t & 3;      // gather/score: 4 lanes per row
    const int d    = t & 127, half = t >> 7; // pooling: 2 threads per d

    if (t < D_DIM) {
        float4 w4 = ((const float4*)Wp)[t];   // Wp[d=t][0..3]
        wpt[0 * D_DIM + t] = w4.x;
        wpt[1 * D_DIM + t] = w4.y;
        wpt[2 * D_DIM + t] = w4.z;
        wpt[3 * D_DIM + t] = w4.w;
    }
    const int cand = cand_ids[b];
    if (t >= 128 && t < 160) {
        int c = t - 128;
        ((float4*)candv)[c] = ((const float4*)(table + (long long)cand * D_DIM))[c];
    }
    rowids[t] = hist[(long long)b * H_LEN + t];

    // chunk-0 prefetch: rowid straight from global (rowids not yet visible).
    // lane q owns bf16 elements q*8 + jj*32 (16B loads).
    bf16x8 v0, v1, v2, v3;
    {
        const int row0 = hist[(long long)b * H_LEN + r];
        const __hip_bfloat16* rp = tableB + (long long)row0 * D_DIM + (q << 3);
        v0 = *(const bf16x8*)(rp + 0 * 32);
        v1 = *(const bf16x8*)(rp + 1 * 32);
        v2 = *(const bf16x8*)(rp + 2 * 32);
        v3 = *(const bf16x8*)(rp + 3 * 32);
    }

    LDS_BARRIER();   // staging visible; chunk-0 prefetch in flight

    float a0 = 0.f, a1 = 0.f, a2 = 0.f, a3 = 0.f;  // pooling acc for (d,half)
    float l0 = 0.f, l1 = 0.f, l2 = 0.f, l3 = 0.f;  // wave-local denom partials

    for (int c = 0; c < NCH; ++c) {
        // --- issue next chunk's gather (consumed next iteration) ---
        bf16x8 u0, u1, u2, u3;
        if (c + 1 < NCH) {
            const int row = rowids[((c + 1) << 6) + r];
            const __hip_bfloat16* rp = tableB + (long long)row * D_DIM + (q << 3);
            u0 = *(const bf16x8*)(rp + 0 * 32);
            u1 = *(const bf16x8*)(rp + 1 * 32);
            u2 = *(const bf16x8*)(rp + 2 * 32);
            u3 = *(const bf16x8*)(rp + 3 * 32);
        }

        // --- scores + raw bf16 tile writes from current chunk's registers ---
        float s0 = 0.f, s1 = 0.f, s2 = 0.f, s3 = 0.f;
        #define DO_J(JJ, VV)                                                    \
        {   const int cb = (q << 3) + (JJ << 5);                                \
            float f0 = bf2f(VV[0]), f1 = bf2f(VV[1]);                           \
            float f2 = bf2f(VV[2]), f3 = bf2f(VV[3]);                           \
            float f4 = bf2f(VV[4]), f5 = bf2f(VV[5]);                           \
            float f6 = bf2f(VV[6]), f7 = bf2f(VV[7]);                           \
            float4 wA, wB;                                                      \
            wA = *(const float4*)(wpt + 0 * D_DIM + cb);                        \
            wB = *(const float4*)(wpt + 0 * D_DIM + cb + 4);                    \
            s0 += f0*wA.x + f1*wA.y + f2*wA.z + f3*wA.w                         \
                + f4*wB.x + f5*wB.y + f6*wB.z + f7*wB.w;                        \
            wA = *(const float4*)(wpt + 1 * D_DIM + cb);                        \
            wB = *(const float4*)(wpt + 1 * D_DIM + cb + 4);                    \
            s1 += f0*wA.x + f1*wA.y + f2*wA.z + f3*wA.w                         \
                + f4*wB.x + f5*wB.y + f6*wB.z + f7*wB.w;                        \
            wA = *(const float4*)(wpt + 2 * D_DIM + cb);                        \
            wB = *(const float4*)(wpt + 2 * D_DIM + cb + 4);                    \
            s2 += f0*wA.x + f1*wA.y + f2*wA.z + f3*wA.w                         \
                + f4*wB.x + f5*wB.y + f6*wB.z + f7*wB.w;                        \
            wA = *(const float4*)(wpt + 3 * D_DIM + cb);                        \
            wB = *(const float4*)(wpt + 3 * D_DIM + cb + 4);                    \
            s3 += f0*wA.x + f1*wA.y + f2*wA.z + f3*wA.w                         \
                + f4*wB.x + f5*wB.y + f6*wB.z + f7*wB.w;                        \
            *(bf16x8*)(tileB + r * TP2 + cb) = VV;                              \
        }
        DO_J(0, v0) DO_J(1, v1) DO_J(2, v2) DO_J(3, v3)
        #undef DO_J

        // combine the 4 q-lanes of each row
        s0 += __shfl_xor(s0, 1); s0 += __shfl_xor(s0, 2);
        s1 += __shfl_xor(s1, 1); s1 += __shfl_xor(s1, 2);
        s2 += __shfl_xor(s2, 1); s2 += __shfl_xor(s2, 2);
        s3 += __shfl_xor(s3, 1); s3 += __shfl_xor(s3, 2);

        float e0 = expf(s0), e1 = expf(s1), e2 = expf(s2), e3 = expf(s3);
        if (q == 0) ((float4*)exps4)[r] = make_float4(e0, e1, e2, e3);

        // wave-sum over this wave's 16 rows
        float t0 = e0, t1 = e1, t2 = e2, t3 = e3;
        #pragma unroll
        for (int off = 4; off <= 32; off <<= 1) {
            t0 += __shfl_xor(t0, off);
            t1 += __shfl_xor(t1, off);
            t2 += __shfl_xor(t2, off);
            t3 += __shfl_xor(t3, off);
        }
        l0 += t0; l1 += t1; l2 += t2; l3 += t3;

        LDS_BARRIER();   // tile + exps4 visible (prefetch stays in flight)

        // --- pooling: acc[k][d] += sum over my 32 chunk rows ---
        // (identical indexing to R6; only the element read is ushort+shift)
        #pragma unroll 8
        for (int i = 0; i < 32; ++i) {
            int hl = (half << 5) + i;
            float4 e4 = ((const float4*)exps4)[hl];   // broadcast
            float  vv = bf2f(tileB[hl * TP2 + d]);
            a0 += e4.x * vv; a1 += e4.y * vv; a2 += e4.z * vv; a3 += e4.w * vv;
        }

        LDS_BARRIER();   // tile/exps4 free for next chunk's writes

        if (c + 1 < NCH) { v0 = u0; v1 = u1; v2 = u2; v3 = u3; }
    }

    __syncthreads();   // full barrier before tile memory reuse
    float* partBp = (float*)tileB;         // 512 floats (tileB = 4352 shorts)
    float* ivbufp = (float*)tileB + 512;   // 512 floats

    if (half == 1) ((float4*)partBp)[d] = make_float4(a0, a1, a2, a3);
    if (lane == 0) ((float4*)lsumW)[w]  = make_float4(l0, l1, l2, l3);
    __syncthreads();

    float s0 = 0.f, s1 = 0.f, s2 = 0.f, s3 = 0.f;
    if (half == 0) {
        float4 pb = ((const float4*)partBp)[d];
        float4 L0 = ((const float4*)lsumW)[0];
        float4 L1 = ((const float4*)lsumW)[1];
        float4 L2 = ((const float4*)lsumW)[2];
        float4 L3 = ((const float4*)lsumW)[3];
        float i0 = 1.f / (L0.x + L1.x + L2.x + L3.x);
        float i1 = 1.f / (L0.y + L1.y + L2.y + L3.y);
        float i2 = 1.f / (L0.z + L1.z + L2.z + L3.z);
        float i3 = 1.f / (L0.w + L1.w + L2.w + L3.w);
        a0 = (a0 + pb.x) * i0;
        a1 = (a1 + pb.y) * i1;
        a2 = (a2 + pb.z) * i2;
        a3 = (a3 + pb.w) * i3;
        ((float4*)ivbufp)[d] = make_float4(a0, a1, a2, a3);
        float cd = candv[d];
        s0 = a0 * cd; s1 = a1 * cd; s2 = a2 * cd; s3 = a3 * cd;
    }
    #pragma unroll
    for (int off = 32; off >= 1; off >>= 1) {
        s0 += __shfl_xor(s0, off);
        s1 += __shfl_xor(s1, off);
        s2 += __shfl_xor(s2, off);
        s3 += __shfl_xor(s3, off);
    }
    if (lane == 0) {
        simred[w][0] = s0; simred[w][1] = s1;
        simred[w][2] = s2; simred[w][3] = s3;
    }
    __syncthreads();

    if (t == 0) {
        float sim[4];
        #pragma unroll
        for (int k = 0; k < 4; ++k)
            sim[k] = simred[0][k] + simred[1][k] + simred[2][k] + simred[3][k];
        int best = 0;
        #pragma unroll
        for (int k = 1; k < 4; ++k) if (sim[k] > sim[best]) best = k;  // first-max
        bestk = best;
    }
    __syncthreads();

    __hip_bfloat16* xrow = Xbf + (long long)b * (2 * D_DIM);
    if (t < 128) xrow[t] = __float2bfloat16(ivbufp[t * 4 + bestk]);
    else         xrow[t] = __float2bfloat16(candv[t - 128]);
}

// ---------------------------------------------------------------------------
// Fallback interest kernel (round-3 verified, fp32 gather, CH=32/NCH=8) —
// used only if the workspace is too small for the bf16 table copy.
// ---------------------------------------------------------------------------
__global__ __launch_bounds__(256, 6) void interest_kernel_f32(
    const int*   __restrict__ cand_ids, const int* __restrict__ hist,
    const float* __restrict__ table, const float* __restrict__ Wp,
    __hip_bfloat16* __restrict__ Xbf)
{
    __shared__ float tile[32 * TPAD];
    __shared__ float wpt[K_HEADS * D_DIM];
    __shared__ float exps4[32 * 4];
    __shared__ float candv[D_DIM];
    __shared__ int   rowids[H_LEN];
    __shared__ float lsumW[16];
    __shared__ float simred[4][K_HEADS];
    __shared__ int   bestk;

    const int b    = blockIdx.x;
    const int t    = threadIdx.x;
    const int lane = t & 63, w = t >> 6;
    const int r    = t >> 3, q = t & 7;
    const int d    = t & 127, half = t >> 7;

    if (t < D_DIM) {
        float4 w4 = ((const float4*)Wp)[t];
        wpt[0 * D_DIM + t] = w4.x; wpt[1 * D_DIM + t] = w4.y;
        wpt[2 * D_DIM + t] = w4.z; wpt[3 * D_DIM + t] = w4.w;
    }
    const int cand = cand_ids[b];
    if (t >= 128 && t < 160) {
        int c = t - 128;
        ((float4*)candv)[c] = ((const float4*)(table + (long long)cand * D_DIM))[c];
    }
    rowids[t] = hist[(long long)b * H_LEN + t];

    float4 v0, v1, v2, v3;
    {
        const int row0 = hist[(long long)b * H_LEN + r];
        const float* rp = table + (long long)row0 * D_DIM + (q << 2);
        v0 = *(const float4*)(rp + 0 * 32); v1 = *(const float4*)(rp + 1 * 32);
        v2 = *(const float4*)(rp + 2 * 32); v3 = *(const float4*)(rp + 3 * 32);
    }
    LDS_BARRIER();

    float a0 = 0.f, a1 = 0.f, a2 = 0.f, a3 = 0.f;
    float l0 = 0.f, l1 = 0.f, l2 = 0.f, l3 = 0.f;

    for (int c = 0; c < 8; ++c) {
        float4 u0, u1, u2, u3;
        if (c + 1 < 8) {
            const int row = rowids[((c + 1) << 5) + r];
            const float* rp = table + (long long)row * D_DIM + (q << 2);
            u0 = *(const float4*)(rp + 0 * 32); u1 = *(const float4*)(rp + 1 * 32);
            u2 = *(const float4*)(rp + 2 * 32); u3 = *(const float4*)(rp + 3 * 32);
        }
        float s0 = 0.f, s1 = 0.f, s2 = 0.f, s3 = 0.f;
        float4 va;
        #define DO_J(JJ, VV)                                                    \
        {   va = VV;                                                            \
            const int cb = (q << 2) + (JJ << 5);                                \
            float4 w0 = *(const float4*)(wpt + 0 * D_DIM + cb);                 \
            float4 w1 = *(const float4*)(wpt + 1 * D_DIM + cb);                 \
            float4 w2 = *(const float4*)(wpt + 2 * D_DIM + cb);                 \
            float4 w3 = *(const float4*)(wpt + 3 * D_DIM + cb);                 \
            s0 += va.x*w0.x + va.y*w0.y + va.z*w0.z + va.w*w0.w;                \
            s1 += va.x*w1.x + va.y*w1.y + va.z*w1.z + va.w*w1.w;                \
            s2 += va.x*w2.x + va.y*w2.y + va.z*w2.z + va.w*w2.w;                \
            s3 += va.x*w3.x + va.y*w3.y + va.z*w3.z + va.w*w3.w;                \
            *(float4*)(tile + r * TPAD + cb) = va;                              \
        }
        DO_J(0, v0) DO_J(1, v1) DO_J(2, v2) DO_J(3, v3)
        #undef DO_J

        s0 += __shfl_xor(s0, 1); s0 += __shfl_xor(s0, 2); s0 += __shfl_xor(s0, 4);
        s1 += __shfl_xor(s1, 1); s1 += __shfl_xor(s1, 2); s1 += __shfl_xor(s1, 4);
        s2 += __shfl_xor(s2, 1); s2 += __shfl_xor(s2, 2); s2 += __shfl_xor(s2, 4);
        s3 += __shfl_xor(s3, 1); s3 += __shfl_xor(s3, 2); s3 += __shfl_xor(s3, 4);

        float e0 = expf(s0), e1 = expf(s1), e2 = expf(s2), e3 = expf(s3);
        if (q == 0) ((float4*)exps4)[r] = make_float4(e0, e1, e2, e3);

        float t0 = e0, t1 = e1, t2 = e2, t3 = e3;
        #pragma unroll
        for (int off = 8; off <= 32; off <<= 1) {
            t0 += __shfl_xor(t0, off); t1 += __shfl_xor(t1, off);
            t2 += __shfl_xor(t2, off); t3 += __shfl_xor(t3, off);
        }
        l0 += t0; l1 += t1; l2 += t2; l3 += t3;

        LDS_BARRIER();
        #pragma unroll
        for (int i = 0; i < 16; ++i) {
            int hl = (half << 4) + i;
            float4 e4 = ((const float4*)exps4)[hl];
            float  vv = tile[hl * TPAD + d];
            a0 += e4.x * vv; a1 += e4.y * vv; a2 += e4.z * vv; a3 += e4.w * vv;
        }
        LDS_BARRIER();
        if (c + 1 < 8) { v0 = u0; v1 = u1; v2 = u2; v3 = u3; }
    }

    __syncthreads();
    float* partBp = tile;
    float* ivbufp = tile + 512;

    if (half == 1) ((float4*)partBp)[d] = make_float4(a0, a1, a2, a3);
    if (lane == 0) ((float4*)lsumW)[w]  = make_float4(l0, l1, l2, l3);
    __syncthreads();

    float s0 = 0.f, s1 = 0.f, s2 = 0.f, s3 = 0.f;
    if (half == 0) {
        float4 pb = ((const float4*)partBp)[d];
        float4 L0 = ((const float4*)lsumW)[0];
        float4 L1 = ((const float4*)lsumW)[1];
        float4 L2 = ((const float4*)lsumW)[2];
        float4 L3 = ((const float4*)lsumW)[3];
        float i0 = 1.f / (L0.x + L1.x + L2.x + L3.x);
        float i1 = 1.f / (L0.y + L1.y + L2.y + L3.y);
        float i2 = 1.f / (L0.z + L1.z + L2.z + L3.z);
        float i3 = 1.f / (L0.w + L1.w + L2.w + L3.w);
        a0 = (a0 + pb.x) * i0; a1 = (a1 + pb.y) * i1;
        a2 = (a2 + pb.z) * i2; a3 = (a3 + pb.w) * i3;
        ((float4*)ivbufp)[d] = make_float4(a0, a1, a2, a3);
        float cd = candv[d];
        s0 = a0 * cd; s1 = a1 * cd; s2 = a2 * cd; s3 = a3 * cd;
    }
    #pragma unroll
    for (int off = 32; off >= 1; off >>= 1) {
        s0 += __shfl_xor(s0, off); s1 += __shfl_xor(s1, off);
        s2 += __shfl_xor(s2, off); s3 += __shfl_xor(s3, off);
    }
    if (lane == 0) {
        simred[w][0] = s0; simred[w][1] = s1;
        simred[w][2] = s2; simred[w][3] = s3;
    }
    __syncthreads();
    if (t == 0) {
        float sim[4];
        #pragma unroll
        for (int k = 0; k < 4; ++k)
            sim[k] = simred[0][k] + simred[1][k] + simred[2][k] + simred[3][k];
        int best = 0;
        #pragma unroll
        for (int k = 1; k < 4; ++k) if (sim[k] > sim[best]) best = k;
        bestk = best;
    }
    __syncthreads();

    __hip_bfloat16* xrow = Xbf + (long long)b * (2 * D_DIM);
    if (t < 128) xrow[t] = __float2bfloat16(ivbufp[t * 4 + bestk]);
    else         xrow[t] = __float2bfloat16(candv[t - 128]);
}

// ---------------------------------------------------------------------------
// Fused conversion. Table part: 16 elems/thread + nontemporal via clang
// ext_vector types (HIP float4/uint4 rejected by the builtin — R7 lesson).
// Blocks 0..6249: table; 6250..6505: weight transpose (32x32 LDS tiles).
// ---------------------------------------------------------------------------
__global__ __launch_bounds__(256) void convert_all(
    const float* __restrict__ table,
    const float* __restrict__ W1, const float* __restrict__ W2,
    __hip_bfloat16* __restrict__ tableB,
    __hip_bfloat16* __restrict__ W1t, __hip_bfloat16* __restrict__ W2t)
{
    __shared__ float tl[32][33];
    int bid = blockIdx.x;
    if (bid < 6250) {                      // table: 25.6M elems / 16 per thread
        long long idx = (long long)bid * 256 + threadIdx.x;   // 16-elem unit
        const cf4* s = (const cf4*)table + idx * 4;
        #pragma unroll
        for (int hh = 0; hh < 2; ++hh) {
            cf4 s0 = __builtin_nontemporal_load(s + hh * 2 + 0);
            cf4 s1 = __builtin_nontemporal_load(s + hh * 2 + 1);
            __hip_bfloat16 o[8];
            o[0] = __float2bfloat16(s0.x); o[1] = __float2bfloat16(s0.y);
            o[2] = __float2bfloat16(s0.z); o[3] = __float2bfloat16(s0.w);
            o[4] = __float2bfloat16(s1.x); o[5] = __float2bfloat16(s1.y);
            o[6] = __float2bfloat16(s1.z); o[7] = __float2bfloat16(s1.w);
            cu4 ov; __builtin_memcpy(&ov, o, 16);
            __builtin_nontemporal_store(ov, (cu4*)(tableB + idx * 16 + hh * 8));
        }
        return;
    }
    bid -= 6250;
    const float* W; __hip_bfloat16* Wt; int K, N;    // W is (K,N); Wt is (N,K)
    if (bid < 128) { W = W1; Wt = W1t; K = 2 * D_DIM; N = H1_DIM; }
    else           { W = W2; Wt = W2t; K = H1_DIM;    N = H2_DIM; bid -= 128; }
    const int ntn = N >> 5;
    const int k0 = (bid / ntn) << 5, n0 = (bid % ntn) << 5;
    const int tx = threadIdx.x & 31, ty = threadIdx.x >> 5;
    #pragma unroll
    for (int j = 0; j < 4; ++j)
        tl[ty + 8 * j][tx] = W[(long long)(k0 + ty + 8 * j) * N + n0 + tx];
    __syncthreads();
    #pragma unroll
    for (int j = 0; j < 4; ++j)
        Wt[(long long)(n0 + ty + 8 * j) * K + k0 + tx] =
            __float2bfloat16(tl[tx][ty + 8 * j]);
}

// Weights-only conversion (fallback path).
__global__ __launch_bounds__(256) void convert_weights(
    const float* __restrict__ W1, const float* __restrict__ W2,
    __hip_bfloat16* __restrict__ W1t, __hip_bfloat16* __restrict__ W2t)
{
    __shared__ float tl[32][33];
    int bid = blockIdx.x;
    const float* W; __hip_bfloat16* Wt; int K, N;
    if (bid < 128) { W = W1; Wt = W1t; K = 2 * D_DIM; N = H1_DIM; }
    else           { W = W2; Wt = W2t; K = H1_DIM;    N = H2_DIM; bid -= 128; }
    const int ntn = N >> 5;
    const int k0 = (bid / ntn) << 5, n0 = (bid % ntn) << 5;
    const int tx = threadIdx.x & 31, ty = threadIdx.x >> 5;
    #pragma unroll
    for (int j = 0; j < 4; ++j)
        tl[ty + 8 * j][tx] = W[(long long)(k0 + ty + 8 * j) * N + n0 + tx];
    __syncthreads();
    #pragma unroll
    for (int j = 0; j < 4; ++j)
        Wt[(long long)(n0 + ty + 8 * j) * K + k0 + tx] =
            __float2bfloat16(tl[tx][ty + 8 * j]);
}

// ---------------------------------------------------------------------------
// Fused MLP tail (R3-verified 512-thread version, unchanged).
// out = sigmoid(relu(relu(X@W1+b1)@W2+b2)@W3+b3).
// MFMA fragment convention (verified): A[lane&15][quad*8+j],
// Bt[n=lane&15][quad*8+j], C col=lane&15 row=quad*4+i.
// ---------------------------------------------------------------------------
__global__ __launch_bounds__(512) void mlp_fused(
    const __hip_bfloat16* __restrict__ X,    // (B, 256)
    const __hip_bfloat16* __restrict__ W1t,  // (512, 256)
    const float* __restrict__ b1,
    const __hip_bfloat16* __restrict__ W2t,  // (256, 512)
    const float* __restrict__ b2,
    const float* __restrict__ W3,            // (256,)
    const float* __restrict__ b3,
    float*       __restrict__ out)           // (B,)
{
    __shared__ __hip_bfloat16 h1[16][H1_DIM + 8];
    __shared__ float          h2[16][H2_DIM + 4];

    const int t    = threadIdx.x;
    const int wave = t >> 6, lane = t & 63;
    const int lm   = lane & 15, quad = lane >> 4;
    const int m0   = blockIdx.x * 16;

    // ---- stage 1: h1 = relu(X @ W1 + b1); 32 N-tiles / 8 waves ----
    const __hip_bfloat16* Ap = X + (long long)(m0 + lm) * (2 * D_DIM) + quad * 8;
    bf16x8 af[8];
    #pragma unroll
    for (int it = 0; it < 8; ++it) af[it] = *(const bf16x8*)(Ap + it * 32);

    #pragma unroll
    for (int tn = 0; tn < 4; ++tn) {
        const int n0 = (wave * 4 + tn) * 16;
        const __hip_bfloat16* Bp = W1t + (long long)(n0 + lm) * (2 * D_DIM) + quad * 8;
        f32x4 acc = {0.f, 0.f, 0.f, 0.f};
        #pragma unroll
        for (int it = 0; it < 8; ++it) {
            bf16x8 bfr = *(const bf16x8*)(Bp + it * 32);
            acc = __builtin_amdgcn_mfma_f32_16x16x32_bf16(af[it], bfr, acc, 0, 0, 0);
        }
        const float bv = b1[n0 + lm];
        #pragma unroll
        for (int i = 0; i < 4; ++i)
            h1[quad * 4 + i][n0 + lm] = __float2bfloat16(fmaxf(acc[i] + bv, 0.f));
    }
    __syncthreads();

    // ---- stage 2: h2 = relu(h1 @ W2 + b2); 16 N-tiles / 8 waves ----
    bf16x8 a2[16];
    #pragma unroll
    for (int it = 0; it < 16; ++it)
        a2[it] = *(const bf16x8*)(&h1[lm][quad * 8 + it * 32]);

    #pragma unroll
    for (int tn = 0; tn < 2; ++tn) {
        const int n0 = (wave * 2 + tn) * 16;
        const __hip_bfloat16* Bp = W2t + (long long)(n0 + lm) * H1_DIM + quad * 8;
        f32x4 acc = {0.f, 0.f, 0.f, 0.f};
        #pragma unroll
        for (int it = 0; it < 16; ++it) {
            bf16x8 bfr = *(const bf16x8*)(Bp + it * 32);
            acc = __builtin_amdgcn_mfma_f32_16x16x32_bf16(a2[it], bfr, acc, 0, 0, 0);
        }
        const float bv = b2[n0 + lm];
        #pragma unroll
        for (int i = 0; i < 4; ++i)
            h2[quad * 4 + i][n0 + lm] = fmaxf(acc[i] + bv, 0.f);
    }
    __syncthreads();

    // ---- head: 32 threads per row, 8 cols each ----
    {
        const int row = t >> 5, c = (t & 31) * 8;
        float s = 0.f;
        #pragma unroll
        for (int j = 0; j < 8; ++j) s += h2[row][c + j] * W3[c + j];
        #pragma unroll
        for (int off = 1; off <= 16; off <<= 1) s += __shfl_xor(s, off);
        if ((lane & 31) == 0)
            out[m0 + row] = 1.f / (1.f + expf(-(s + b3[0])));
    }
}

// ---------------------------------------------------------------------------
extern "C" void kernel_launch(void* const* d_in, const int* in_sizes, int n_in,
                              void* d_out, int out_size, void* d_ws, size_t ws_size,
                              hipStream_t stream) {
    const int*   cand  = (const int*)  d_in[1];
    const int*   hist  = (const int*)  d_in[2];
    const float* table = (const float*)d_in[3];
    const float* Wp    = (const float*)d_in[4];
    const float* W1    = (const float*)d_in[5];
    const float* b1    = (const float*)d_in[6];
    const float* W2    = (const float*)d_in[7];
    const float* b2    = (const float*)d_in[8];
    const float* W3    = (const float*)d_in[9];
    const float* b3    = (const float*)d_in[10];
    float* out = (float*)d_out;

    // ws layout (16B-aligned regions); tableB last so the fallback layout is a prefix
    char* p = (char*)d_ws;
    __hip_bfloat16* Xbf = (__hip_bfloat16*)p;  p += (size_t)B_SZ * 2 * D_DIM * 2;   // 2 MB
    __hip_bfloat16* W1t = (__hip_bfloat16*)p;  p += (size_t)H1_DIM * 2 * D_DIM * 2; // 512 KB
    __hip_bfloat16* W2t = (__hip_bfloat16*)p;  p += (size_t)H1_DIM * H2_DIM * 2;    // 256 KB
    __hip_bfloat16* tableB = (__hip_bfloat16*)p;
    const size_t need = ((char*)tableB - (char*)d_ws) + (size_t)NUM_ITEMS * D_DIM * 2;

    if (ws_size >= need) {
        convert_all<<<6250 + 256, 256, 0, stream>>>(table, W1, W2, tableB, W1t, W2t);
        interest_kernel_bf16<<<B_SZ, 256, 0, stream>>>(cand, hist, table, tableB, Wp, Xbf);
    } else {
        convert_weights<<<256, 256, 0, stream>>>(W1, W2, W1t, W2t);
        interest_kernel_f32<<<B_SZ, 256, 0, stream>>>(cand, hist, table, Wp, Xbf);
    }
    mlp_fused<<<B_SZ / 16, 512, 0, stream>>>(Xbf, W1t, b1, W2t, b2, W3, b3, out);
}

// Round 9
// 252.757 us; speedup vs baseline: 1.1155x; 1.1155x over previous
//
#include <hip/hip_runtime.h>
#include <hip/hip_bf16.h>
#include <math.h>

#define B_SZ   4096
#define H_LEN  256
#define D_DIM  128
#define K_HEADS 4
#define H1_DIM 512
#define H2_DIM 256
#define NUM_ITEMS 200000

#define CH     64     // history rows per chunk
#define NCH    4      // chunks
#define TPAD   132    // fp32 tile row stride (fallback kernel only)

typedef __attribute__((ext_vector_type(8))) short bf16x8;   // 8 bf16 (4 VGPRs)
typedef __attribute__((ext_vector_type(4))) float f32x4;

// Raw barrier: LDS-visibility only (no vmcnt drain — keeps DMAs in flight).
#define LDS_BARRIER() do {                                   \
    asm volatile("s_waitcnt lgkmcnt(0)" ::: "memory");       \
    __builtin_amdgcn_s_barrier();                            \
} while (0)

#define WAITVM4() asm volatile("s_waitcnt vmcnt(4)" ::: "memory")
#define WAITVM0() asm volatile("s_waitcnt vmcnt(0)" ::: "memory")

__device__ __forceinline__ float bf2f(short s) {
    unsigned u = ((unsigned)(unsigned short)s) << 16;
    float f; __builtin_memcpy(&f, &u, 4); return f;
}

// global->LDS direct 16B DMA. LDS dest = wave-uniform base + lane*16 (HW rule,
// guide m104/m108); global src IS per-lane (m173).
__device__ __forceinline__ void gl_lds16(const void* g, void* l) {
    __builtin_amdgcn_global_load_lds(
        (const __attribute__((address_space(1))) void*)g,
        (__attribute__((address_space(3))) void*)l, 16, 0, 0);
}

// ---------------------------------------------------------------------------
// Kernel 1 (primary): interest extraction with PRECOMPUTED per-item exp-scores.
// R8 lesson: structure was VALU/issue-bound (91-93 us across 4 configs; occupancy
// and LDS size were not the lever). This version removes the entire score phase
// from the loop (E[item][k]=exp(item . Wp_k) precomputed in convert_all) and
// streams the gather via global_load_lds (no VGPR round-trip, no prefetch regs).
// Double-buffered 2x16KB tiles, counted vmcnt(4) (never 0 in-loop).
// Pooling + epilogue verbatim from R8 (passing, absmax 0.0039).
// ---------------------------------------------------------------------------
__global__ __launch_bounds__(256, 4) void interest_dma(
    const int*   __restrict__ cand_ids,        // (B,)
    const int*   __restrict__ hist,            // (B, H)
    const float* __restrict__ table,           // (NUM_ITEMS, D) fp32 (candv only)
    const __hip_bfloat16* __restrict__ tableB, // (NUM_ITEMS, D) bf16
    const float* __restrict__ Etab,            // (NUM_ITEMS, 4) exp(scores)
    __hip_bfloat16* __restrict__ Xbf)          // (B, 2D) bf16: [selected | cand]
{
    __shared__ __align__(16) short tile2[2][CH][D_DIM]; // 32 KB, linear rows (DMA)
    __shared__ float exps[H_LEN][4];                    // 4 KB: E for all 256 rows
    __shared__ float candv[D_DIM];                      // 512 B
    __shared__ int   rowids[H_LEN];                     // 1 KB
    __shared__ float lsumW[16];                         // [wave][k] denom partials
    __shared__ int   bestk;

    const int b    = blockIdx.x;
    const int t    = threadIdx.x;
    const int lane = t & 63, w = t >> 6;
    const int d    = t & 127, half = t >> 7;   // pooling: 2 threads per d

    const int cand = cand_ids[b];
    if (t < 32)
        ((float4*)candv)[t] = ((const float4*)(table + (long long)cand * D_DIM))[t];
    rowids[t] = hist[(long long)b * H_LEN + t];
    __syncthreads();   // rowids/candv visible (nothing to overlap yet)

    // E gather first (oldest in vm queue -> compiler waits only this one),
    // then DMA chunks 0 and 1 (4 issues/wave each).
    float4 ev = ((const float4*)Etab)[rowids[t]];

    #pragma unroll
    for (int cc = 0; cc < 2; ++cc) {
        #pragma unroll
        for (int i = 0; i < 4; ++i) {
            const int rloc = w * 16 + i * 4 + (lane >> 4);   // row within chunk
            const int grow = rowids[(cc << 6) + rloc];
            const __hip_bfloat16* gp =
                tableB + (long long)grow * D_DIM + ((lane & 15) << 3);
            gl_lds16(gp, &tile2[cc][w * 16 + i * 4][0]);     // uniform base/wave
        }
    }

    // exps staging + denominators (one wave-reduce; rows t covered per wave)
    ((float4*)exps)[t] = ev;
    float l0 = ev.x, l1 = ev.y, l2 = ev.z, l3 = ev.w;
    #pragma unroll
    for (int off = 1; off <= 32; off <<= 1) {
        l0 += __shfl_xor(l0, off);
        l1 += __shfl_xor(l1, off);
        l2 += __shfl_xor(l2, off);
        l3 += __shfl_xor(l3, off);
    }
    if (lane == 0) ((float4*)lsumW)[w] = make_float4(l0, l1, l2, l3);

    float a0 = 0.f, a1 = 0.f, a2 = 0.f, a3 = 0.f;  // pooling acc for (d,half)

    for (int c = 0; c < NCH; ++c) {
        // wait own chunk-c DMAs (4 newer = chunk c+1 stay in flight); last iter
        // has nothing newer -> full drain.
        if (c < NCH - 1) WAITVM4(); else WAITVM0();
        LDS_BARRIER();   // all waves' chunk-c rows + exps/lsumW visible

        // --- pooling: acc[k][d] += sum over my 32 chunk rows (R8-identical) ---
        #pragma unroll 8
        for (int i = 0; i < 32; ++i) {
            const int hl = (half << 5) + i;
            float4 e4 = ((const float4*)exps)[(c << 6) + hl];   // broadcast
            float  vv = bf2f(tile2[c & 1][hl][d]);
            a0 += e4.x * vv; a1 += e4.y * vv; a2 += e4.z * vv; a3 += e4.w * vv;
        }

        LDS_BARRIER();   // all reads of buf (c&1) done -> safe to overwrite

        if (c + 2 < NCH) {
            #pragma unroll
            for (int i = 0; i < 4; ++i) {
                const int rloc = w * 16 + i * 4 + (lane >> 4);
                const int grow = rowids[((c + 2) << 6) + rloc];
                const __hip_bfloat16* gp =
                    tableB + (long long)grow * D_DIM + ((lane & 15) << 3);
                gl_lds16(gp, &tile2[c & 1][w * 16 + i * 4][0]);
            }
        }
    }

    __syncthreads();   // vmcnt already 0; full barrier before tile reuse
    float* partBp = (float*)tile2;         // 512 floats scratch
    float* ivbufp = (float*)tile2 + 512;   // 512 floats [d][k]

    if (half == 1) ((float4*)partBp)[d] = make_float4(a0, a1, a2, a3);
    __syncthreads();

    float s0 = 0.f, s1 = 0.f, s2 = 0.f, s3 = 0.f;
    if (half == 0) {
        float4 pb = ((const float4*)partBp)[d];
        float4 L0 = ((const float4*)lsumW)[0];
        float4 L1 = ((const float4*)lsumW)[1];
        float4 L2 = ((const float4*)lsumW)[2];
        float4 L3 = ((const float4*)lsumW)[3];
        float i0 = 1.f / (L0.x + L1.x + L2.x + L3.x);
        float i1 = 1.f / (L0.y + L1.y + L2.y + L3.y);
        float i2 = 1.f / (L0.z + L1.z + L2.z + L3.z);
        float i3 = 1.f / (L0.w + L1.w + L2.w + L3.w);
        a0 = (a0 + pb.x) * i0;
        a1 = (a1 + pb.y) * i1;
        a2 = (a2 + pb.z) * i2;
        a3 = (a3 + pb.w) * i3;
        ((float4*)ivbufp)[d] = make_float4(a0, a1, a2, a3);
        float cd = candv[d];
        s0 = a0 * cd; s1 = a1 * cd; s2 = a2 * cd; s3 = a3 * cd;
    }
    #pragma unroll
    for (int off = 32; off >= 1; off >>= 1) {
        s0 += __shfl_xor(s0, off);
        s1 += __shfl_xor(s1, off);
        s2 += __shfl_xor(s2, off);
        s3 += __shfl_xor(s3, off);
    }
    __shared__ float simred[4][K_HEADS];
    if (lane == 0) {
        simred[w][0] = s0; simred[w][1] = s1;
        simred[w][2] = s2; simred[w][3] = s3;
    }
    __syncthreads();

    if (t == 0) {
        float sim[4];
        #pragma unroll
        for (int k = 0; k < 4; ++k)
            sim[k] = simred[0][k] + simred[1][k] + simred[2][k] + simred[3][k];
        int best = 0;
        #pragma unroll
        for (int k = 1; k < 4; ++k) if (sim[k] > sim[best]) best = k;  // first-max
        bestk = best;
    }
    __syncthreads();

    __hip_bfloat16* xrow = Xbf + (long long)b * (2 * D_DIM);
    if (t < 128) xrow[t] = __float2bfloat16(ivbufp[t * 4 + bestk]);
    else         xrow[t] = __float2bfloat16(candv[t - 128]);
}

// ---------------------------------------------------------------------------
// Fallback interest kernel (round-3 verified, fp32 gather, CH=32/NCH=8) —
// used only if the workspace is too small for the bf16 table + E copy.
// ---------------------------------------------------------------------------
__global__ __launch_bounds__(256, 6) void interest_kernel_f32(
    const int*   __restrict__ cand_ids, const int* __restrict__ hist,
    const float* __restrict__ table, const float* __restrict__ Wp,
    __hip_bfloat16* __restrict__ Xbf)
{
    __shared__ float tile[32 * TPAD];
    __shared__ float wpt[K_HEADS * D_DIM];
    __shared__ float exps4[32 * 4];
    __shared__ float candv[D_DIM];
    __shared__ int   rowids[H_LEN];
    __shared__ float lsumW[16];
    __shared__ float simred[4][K_HEADS];
    __shared__ int   bestk;

    const int b    = blockIdx.x;
    const int t    = threadIdx.x;
    const int lane = t & 63, w = t >> 6;
    const int r    = t >> 3, q = t & 7;
    const int d    = t & 127, half = t >> 7;

    if (t < D_DIM) {
        float4 w4 = ((const float4*)Wp)[t];
        wpt[0 * D_DIM + t] = w4.x; wpt[1 * D_DIM + t] = w4.y;
        wpt[2 * D_DIM + t] = w4.z; wpt[3 * D_DIM + t] = w4.w;
    }
    const int cand = cand_ids[b];
    if (t >= 128 && t < 160) {
        int c = t - 128;
        ((float4*)candv)[c] = ((const float4*)(table + (long long)cand * D_DIM))[c];
    }
    rowids[t] = hist[(long long)b * H_LEN + t];

    float4 v0, v1, v2, v3;
    {
        const int row0 = hist[(long long)b * H_LEN + r];
        const float* rp = table + (long long)row0 * D_DIM + (q << 2);
        v0 = *(const float4*)(rp + 0 * 32); v1 = *(const float4*)(rp + 1 * 32);
        v2 = *(const float4*)(rp + 2 * 32); v3 = *(const float4*)(rp + 3 * 32);
    }
    LDS_BARRIER();

    float a0 = 0.f, a1 = 0.f, a2 = 0.f, a3 = 0.f;
    float l0 = 0.f, l1 = 0.f, l2 = 0.f, l3 = 0.f;

    for (int c = 0; c < 8; ++c) {
        float4 u0, u1, u2, u3;
        if (c + 1 < 8) {
            const int row = rowids[((c + 1) << 5) + r];
            const float* rp = table + (long long)row * D_DIM + (q << 2);
            u0 = *(const float4*)(rp + 0 * 32); u1 = *(const float4*)(rp + 1 * 32);
            u2 = *(const float4*)(rp + 2 * 32); u3 = *(const float4*)(rp + 3 * 32);
        }
        float s0 = 0.f, s1 = 0.f, s2 = 0.f, s3 = 0.f;
        float4 va;
        #define DO_J(JJ, VV)                                                    \
        {   va = VV;                                                            \
            const int cb = (q << 2) + (JJ << 5);                                \
            float4 w0 = *(const float4*)(wpt + 0 * D_DIM + cb);                 \
            float4 w1 = *(const float4*)(wpt + 1 * D_DIM + cb);                 \
            float4 w2 = *(const float4*)(wpt + 2 * D_DIM + cb);                 \
            float4 w3 = *(const float4*)(wpt + 3 * D_DIM + cb);                 \
            s0 += va.x*w0.x + va.y*w0.y + va.z*w0.z + va.w*w0.w;                \
            s1 += va.x*w1.x + va.y*w1.y + va.z*w1.z + va.w*w1.w;                \
            s2 += va.x*w2.x + va.y*w2.y + va.z*w2.z + va.w*w2.w;                \
            s3 += va.x*w3.x + va.y*w3.y + va.z*w3.z + va.w*w3.w;                \
            *(float4*)(tile + r * TPAD + cb) = va;                              \
        }
        DO_J(0, v0) DO_J(1, v1) DO_J(2, v2) DO_J(3, v3)
        #undef DO_J

        s0 += __shfl_xor(s0, 1); s0 += __shfl_xor(s0, 2); s0 += __shfl_xor(s0, 4);
        s1 += __shfl_xor(s1, 1); s1 += __shfl_xor(s1, 2); s1 += __shfl_xor(s1, 4);
        s2 += __shfl_xor(s2, 1); s2 += __shfl_xor(s2, 2); s2 += __shfl_xor(s2, 4);
        s3 += __shfl_xor(s3, 1); s3 += __shfl_xor(s3, 2); s3 += __shfl_xor(s3, 4);

        float e0 = expf(s0), e1 = expf(s1), e2 = expf(s2), e3 = expf(s3);
        if (q == 0) ((float4*)exps4)[r] = make_float4(e0, e1, e2, e3);

        float t0 = e0, t1 = e1, t2 = e2, t3 = e3;
        #pragma unroll
        for (int off = 8; off <= 32; off <<= 1) {
            t0 += __shfl_xor(t0, off); t1 += __shfl_xor(t1, off);
            t2 += __shfl_xor(t2, off); t3 += __shfl_xor(t3, off);
        }
        l0 += t0; l1 += t1; l2 += t2; l3 += t3;

        LDS_BARRIER();
        #pragma unroll
        for (int i = 0; i < 16; ++i) {
            int hl = (half << 4) + i;
            float4 e4 = ((const float4*)exps4)[hl];
            float  vv = tile[hl * TPAD + d];
            a0 += e4.x * vv; a1 += e4.y * vv; a2 += e4.z * vv; a3 += e4.w * vv;
        }
        LDS_BARRIER();
        if (c + 1 < 8) { v0 = u0; v1 = u1; v2 = u2; v3 = u3; }
    }

    __syncthreads();
    float* partBp = tile;
    float* ivbufp = tile + 512;

    if (half == 1) ((float4*)partBp)[d] = make_float4(a0, a1, a2, a3);
    if (lane == 0) ((float4*)lsumW)[w]  = make_float4(l0, l1, l2, l3);
    __syncthreads();

    float s0 = 0.f, s1 = 0.f, s2 = 0.f, s3 = 0.f;
    if (half == 0) {
        float4 pb = ((const float4*)partBp)[d];
        float4 L0 = ((const float4*)lsumW)[0];
        float4 L1 = ((const float4*)lsumW)[1];
        float4 L2 = ((const float4*)lsumW)[2];
        float4 L3 = ((const float4*)lsumW)[3];
        float i0 = 1.f / (L0.x + L1.x + L2.x + L3.x);
        float i1 = 1.f / (L0.y + L1.y + L2.y + L3.y);
        float i2 = 1.f / (L0.z + L1.z + L2.z + L3.z);
        float i3 = 1.f / (L0.w + L1.w + L2.w + L3.w);
        a0 = (a0 + pb.x) * i0; a1 = (a1 + pb.y) * i1;
        a2 = (a2 + pb.z) * i2; a3 = (a3 + pb.w) * i3;
        ((float4*)ivbufp)[d] = make_float4(a0, a1, a2, a3);
        float cd = candv[d];
        s0 = a0 * cd; s1 = a1 * cd; s2 = a2 * cd; s3 = a3 * cd;
    }
    #pragma unroll
    for (int off = 32; off >= 1; off >>= 1) {
        s0 += __shfl_xor(s0, off); s1 += __shfl_xor(s1, off);
        s2 += __shfl_xor(s2, off); s3 += __shfl_xor(s3, off);
    }
    if (lane == 0) {
        simred[w][0] = s0; simred[w][1] = s1;
        simred[w][2] = s2; simred[w][3] = s3;
    }
    __syncthreads();
    if (t == 0) {
        float sim[4];
        #pragma unroll
        for (int k = 0; k < 4; ++k)
            sim[k] = simred[0][k] + simred[1][k] + simred[2][k] + simred[3][k];
        int best = 0;
        #pragma unroll
        for (int k = 1; k < 4; ++k) if (sim[k] > sim[best]) best = k;
        bestk = best;
    }
    __syncthreads();

    __hip_bfloat16* xrow = Xbf + (long long)b * (2 * D_DIM);
    if (t < 128) xrow[t] = __float2bfloat16(ivbufp[t * 4 + bestk]);
    else         xrow[t] = __float2bfloat16(candv[t - 128]);
}

// ---------------------------------------------------------------------------
// Fused conversion + SCORE PRECOMPUTE. Table blocks (0..6249): 32 rows/block,
// 8 threads/row; each thread converts 16 elems AND accumulates the 4 Wp dots
// (free — kernel is stream-bound). Lane q==0 writes E[row]=exp(score) fp32.
// Weight blocks (6250..6505): 32x32 LDS transpose as before.
// ---------------------------------------------------------------------------
__global__ __launch_bounds__(256) void convert_all(
    const float* __restrict__ table, const float* __restrict__ Wp,
    const float* __restrict__ W1, const float* __restrict__ W2,
    __hip_bfloat16* __restrict__ tableB, float* __restrict__ Etab,
    __hip_bfloat16* __restrict__ W1t, __hip_bfloat16* __restrict__ W2t)
{
    __shared__ float tl[32][33];
    __shared__ float wpt[K_HEADS][D_DIM];
    int bid = blockIdx.x;
    const int tid = threadIdx.x;
    if (bid < 6250) {
        if (tid < D_DIM) {
            float4 w4 = ((const float4*)Wp)[tid];
            wpt[0][tid] = w4.x; wpt[1][tid] = w4.y;
            wpt[2][tid] = w4.z; wpt[3][tid] = w4.w;
        }
        __syncthreads();
        const int r = tid >> 3, q = tid & 7;          // 32 rows x 8 threads
        const long long row = (long long)bid * 32 + r;
        const float* src = table + row * D_DIM + q * 16;
        float x[16];
        #pragma unroll
        for (int j = 0; j < 4; ++j) {
            float4 v = ((const float4*)src)[j];
            x[4*j] = v.x; x[4*j+1] = v.y; x[4*j+2] = v.z; x[4*j+3] = v.w;
        }
        __hip_bfloat16 o[16];
        #pragma unroll
        for (int j = 0; j < 16; ++j) o[j] = __float2bfloat16(x[j]);
        __hip_bfloat16* dst = tableB + row * D_DIM + q * 16;
        ((uint4*)dst)[0] = *(uint4*)(o);
        ((uint4*)dst)[1] = *(uint4*)(o + 8);

        float s0 = 0.f, s1 = 0.f, s2 = 0.f, s3 = 0.f;
        const int cb = q * 16;
        #pragma unroll
        for (int j = 0; j < 16; ++j) {
            s0 += x[j] * wpt[0][cb + j];
            s1 += x[j] * wpt[1][cb + j];
            s2 += x[j] * wpt[2][cb + j];
            s3 += x[j] * wpt[3][cb + j];
        }
        s0 += __shfl_xor(s0, 1); s0 += __shfl_xor(s0, 2); s0 += __shfl_xor(s0, 4);
        s1 += __shfl_xor(s1, 1); s1 += __shfl_xor(s1, 2); s1 += __shfl_xor(s1, 4);
        s2 += __shfl_xor(s2, 1); s2 += __shfl_xor(s2, 2); s2 += __shfl_xor(s2, 4);
        s3 += __shfl_xor(s3, 1); s3 += __shfl_xor(s3, 2); s3 += __shfl_xor(s3, 4);
        if (q == 0)
            ((float4*)Etab)[row] = make_float4(expf(s0), expf(s1), expf(s2), expf(s3));
        return;
    }
    bid -= 6250;
    const float* W; __hip_bfloat16* Wt; int K, N;    // W is (K,N); Wt is (N,K)
    if (bid < 128) { W = W1; Wt = W1t; K = 2 * D_DIM; N = H1_DIM; }
    else           { W = W2; Wt = W2t; K = H1_DIM;    N = H2_DIM; bid -= 128; }
    const int ntn = N >> 5;
    const int k0 = (bid / ntn) << 5, n0 = (bid % ntn) << 5;
    const int tx = tid & 31, ty = tid >> 5;
    #pragma unroll
    for (int j = 0; j < 4; ++j)
        tl[ty + 8 * j][tx] = W[(long long)(k0 + ty + 8 * j) * N + n0 + tx];
    __syncthreads();
    #pragma unroll
    for (int j = 0; j < 4; ++j)
        Wt[(long long)(n0 + ty + 8 * j) * K + k0 + tx] =
            __float2bfloat16(tl[tx][ty + 8 * j]);
}

// Weights-only conversion (fallback path).
__global__ __launch_bounds__(256) void convert_weights(
    const float* __restrict__ W1, const float* __restrict__ W2,
    __hip_bfloat16* __restrict__ W1t, __hip_bfloat16* __restrict__ W2t)
{
    __shared__ float tl[32][33];
    int bid = blockIdx.x;
    const float* W; __hip_bfloat16* Wt; int K, N;
    if (bid < 128) { W = W1; Wt = W1t; K = 2 * D_DIM; N = H1_DIM; }
    else           { W = W2; Wt = W2t; K = H1_DIM;    N = H2_DIM; bid -= 128; }
    const int ntn = N >> 5;
    const int k0 = (bid / ntn) << 5, n0 = (bid % ntn) << 5;
    const int tx = threadIdx.x & 31, ty = threadIdx.x >> 5;
    #pragma unroll
    for (int j = 0; j < 4; ++j)
        tl[ty + 8 * j][tx] = W[(long long)(k0 + ty + 8 * j) * N + n0 + tx];
    __syncthreads();
    #pragma unroll
    for (int j = 0; j < 4; ++j)
        Wt[(long long)(n0 + ty + 8 * j) * K + k0 + tx] =
            __float2bfloat16(tl[tx][ty + 8 * j]);
}

// ---------------------------------------------------------------------------
// Fused MLP tail (R3-verified 512-thread version, unchanged).
// ---------------------------------------------------------------------------
__global__ __launch_bounds__(512) void mlp_fused(
    const __hip_bfloat16* __restrict__ X,    // (B, 256)
    const __hip_bfloat16* __restrict__ W1t,  // (512, 256)
    const float* __restrict__ b1,
    const __hip_bfloat16* __restrict__ W2t,  // (256, 512)
    const float* __restrict__ b2,
    const float* __restrict__ W3,            // (256,)
    const float* __restrict__ b3,
    float*       __restrict__ out)           // (B,)
{
    __shared__ __hip_bfloat16 h1[16][H1_DIM + 8];
    __shared__ float          h2[16][H2_DIM + 4];

    const int t    = threadIdx.x;
    const int wave = t >> 6, lane = t & 63;
    const int lm   = lane & 15, quad = lane >> 4;
    const int m0   = blockIdx.x * 16;

    const __hip_bfloat16* Ap = X + (long long)(m0 + lm) * (2 * D_DIM) + quad * 8;
    bf16x8 af[8];
    #pragma unroll
    for (int it = 0; it < 8; ++it) af[it] = *(const bf16x8*)(Ap + it * 32);

    #pragma unroll
    for (int tn = 0; tn < 4; ++tn) {
        const int n0 = (wave * 4 + tn) * 16;
        const __hip_bfloat16* Bp = W1t + (long long)(n0 + lm) * (2 * D_DIM) + quad * 8;
        f32x4 acc = {0.f, 0.f, 0.f, 0.f};
        #pragma unroll
        for (int it = 0; it < 8; ++it) {
            bf16x8 bfr = *(const bf16x8*)(Bp + it * 32);
            acc = __builtin_amdgcn_mfma_f32_16x16x32_bf16(af[it], bfr, acc, 0, 0, 0);
        }
        const float bv = b1[n0 + lm];
        #pragma unroll
        for (int i = 0; i < 4; ++i)
            h1[quad * 4 + i][n0 + lm] = __float2bfloat16(fmaxf(acc[i] + bv, 0.f));
    }
    __syncthreads();

    bf16x8 a2[16];
    #pragma unroll
    for (int it = 0; it < 16; ++it)
        a2[it] = *(const bf16x8*)(&h1[lm][quad * 8 + it * 32]);

    #pragma unroll
    for (int tn = 0; tn < 2; ++tn) {
        const int n0 = (wave * 2 + tn) * 16;
        const __hip_bfloat16* Bp = W2t + (long long)(n0 + lm) * H1_DIM + quad * 8;
        f32x4 acc = {0.f, 0.f, 0.f, 0.f};
        #pragma unroll
        for (int it = 0; it < 16; ++it) {
            bf16x8 bfr = *(const bf16x8*)(Bp + it * 32);
            acc = __builtin_amdgcn_mfma_f32_16x16x32_bf16(a2[it], bfr, acc, 0, 0, 0);
        }
        const float bv = b2[n0 + lm];
        #pragma unroll
        for (int i = 0; i < 4; ++i)
            h2[quad * 4 + i][n0 + lm] = fmaxf(acc[i] + bv, 0.f);
    }
    __syncthreads();

    {
        const int row = t >> 5, c = (t & 31) * 8;
        float s = 0.f;
        #pragma unroll
        for (int j = 0; j < 8; ++j) s += h2[row][c + j] * W3[c + j];
        #pragma unroll
        for (int off = 1; off <= 16; off <<= 1) s += __shfl_xor(s, off);
        if ((lane & 31) == 0)
            out[m0 + row] = 1.f / (1.f + expf(-(s + b3[0])));
    }
}

// ---------------------------------------------------------------------------
extern "C" void kernel_launch(void* const* d_in, const int* in_sizes, int n_in,
                              void* d_out, int out_size, void* d_ws, size_t ws_size,
                              hipStream_t stream) {
    const int*   cand  = (const int*)  d_in[1];
    const int*   hist  = (const int*)  d_in[2];
    const float* table = (const float*)d_in[3];
    const float* Wp    = (const float*)d_in[4];
    const float* W1    = (const float*)d_in[5];
    const float* b1    = (const float*)d_in[6];
    const float* W2    = (const float*)d_in[7];
    const float* b2    = (const float*)d_in[8];
    const float* W3    = (const float*)d_in[9];
    const float* b3    = (const float*)d_in[10];
    float* out = (float*)d_out;

    // ws layout (16B-aligned regions); tableB/Etab last (fallback = prefix)
    char* p = (char*)d_ws;
    __hip_bfloat16* Xbf = (__hip_bfloat16*)p;  p += (size_t)B_SZ * 2 * D_DIM * 2;   // 2 MB
    __hip_bfloat16* W1t = (__hip_bfloat16*)p;  p += (size_t)H1_DIM * 2 * D_DIM * 2; // 512 KB
    __hip_bfloat16* W2t = (__hip_bfloat16*)p;  p += (size_t)H1_DIM * H2_DIM * 2;    // 256 KB
    __hip_bfloat16* tableB = (__hip_bfloat16*)p; p += (size_t)NUM_ITEMS * D_DIM * 2;// 51.2 MB
    float*          Etab   = (float*)p;
    const size_t need = ((char*)Etab - (char*)d_ws) + (size_t)NUM_ITEMS * 4 * 4;

    if (ws_size >= need) {
        convert_all<<<6250 + 256, 256, 0, stream>>>(table, Wp, W1, W2,
                                                    tableB, Etab, W1t, W2t);
        interest_dma<<<B_SZ, 256, 0, stream>>>(cand, hist, table, tableB, Etab, Xbf);
    } else {
        convert_weights<<<256, 256, 0, stream>>>(W1, W2, W1t, W2t);
        interest_kernel_f32<<<B_SZ, 256, 0, stream>>>(cand, hist, table, Wp, Xbf);
    }
    mlp_fused<<<B_SZ / 16, 512, 0, stream>>>(Xbf, W1t, b1, W2t, b2, W3, b3, out);
}